// Round 1
// baseline (3542.759 us; speedup 1.0000x reference)
//
#include <hip/hip_runtime.h>
#include <math.h>

#define N_NODES 50000
#define N_EDGES 800000

// ---------- helpers ----------
__device__ __forceinline__ unsigned enc_f(float x) {
  unsigned b = __float_as_uint(x);
  return (b & 0x80000000u) ? ~b : (b | 0x80000000u);
}
__device__ __forceinline__ float dec_f(unsigned u) {
  unsigned b = (u & 0x80000000u) ? (u & 0x7fffffffu) : ~u;
  return __uint_as_float(b);
}
__device__ __forceinline__ float leaky(float x) { return x >= 0.f ? x : 0.2f * x; }

// ---------- fp32 tiled GEMM: C(MxN) = A(MxK) @ B(KxN) [+ bias] ----------
// 64x64 tile, BK=16, 256 threads, 4x4 microtile per thread.
template <bool ADD_BIAS>
__launch_bounds__(256)
__global__ void sgemm_k(const float* __restrict__ A, const float* __restrict__ B,
                        const float* __restrict__ bias, float* __restrict__ C,
                        int M, int K, int N) {
  __shared__ float As[16][68];  // +4 pad: breaks 4-way bank conflict on transposed stores
  __shared__ float Bs[16][64];
  const int tid = threadIdx.x;
  const int bm0 = blockIdx.x * 64;
  const int bn0 = blockIdx.y * 64;
  const int tm0 = (tid >> 4) * 4;
  const int tn0 = (tid & 15) * 4;
  const int am = tid >> 2;
  const int ak = (tid & 3) * 4;
  const int bk = tid >> 4;
  const int bn = (tid & 15) * 4;
  float acc[4][4] = {{0.f, 0.f, 0.f, 0.f}};

  for (int k0 = 0; k0 < K; k0 += 16) {
    float4 av = make_float4(0.f, 0.f, 0.f, 0.f);
    if (bm0 + am < M) av = *(const float4*)(A + (size_t)(bm0 + am) * K + k0 + ak);
    As[ak + 0][am] = av.x;
    As[ak + 1][am] = av.y;
    As[ak + 2][am] = av.z;
    As[ak + 3][am] = av.w;
    *(float4*)&Bs[bk][bn] = *(const float4*)(B + (size_t)(k0 + bk) * N + bn0 + bn);
    __syncthreads();
#pragma unroll
    for (int k = 0; k < 16; ++k) {
      float4 a = *(float4*)&As[k][tm0];
      float4 b = *(float4*)&Bs[k][tn0];
      acc[0][0] += a.x * b.x; acc[0][1] += a.x * b.y; acc[0][2] += a.x * b.z; acc[0][3] += a.x * b.w;
      acc[1][0] += a.y * b.x; acc[1][1] += a.y * b.y; acc[1][2] += a.y * b.z; acc[1][3] += a.y * b.w;
      acc[2][0] += a.z * b.x; acc[2][1] += a.z * b.y; acc[2][2] += a.z * b.z; acc[2][3] += a.z * b.w;
      acc[3][0] += a.w * b.x; acc[3][1] += a.w * b.y; acc[3][2] += a.w * b.z; acc[3][3] += a.w * b.w;
    }
    __syncthreads();
  }
#pragma unroll
  for (int i = 0; i < 4; ++i) {
    int m = bm0 + tm0 + i;
    if (m >= M) break;
    float4 v = make_float4(acc[i][0], acc[i][1], acc[i][2], acc[i][3]);
    if (ADD_BIAS) {
      v.x += bias[bn0 + tn0 + 0];
      v.y += bias[bn0 + tn0 + 1];
      v.z += bias[bn0 + tn0 + 2];
      v.w += bias[bn0 + tn0 + 3];
    }
    *(float4*)(C + (size_t)m * N + bn0 + tn0) = v;
  }
}

// ---------- el/er row-dots, layer 1 (H=4, D=64) ----------
// one wave per node; lane holds 4 consecutive feats; head = lane/16.
__launch_bounds__(256)
__global__ void rowdot1_k(const float* __restrict__ ft, const float* __restrict__ al,
                          const float* __restrict__ ar, float* __restrict__ el,
                          float* __restrict__ er) {
  int node = blockIdx.x * 4 + (threadIdx.x >> 6);
  int lane = threadIdx.x & 63;
  if (node >= N_NODES) return;
  float4 f = *(const float4*)(ft + (size_t)node * 256 + lane * 4);
  float4 a = *(const float4*)(al + lane * 4);
  float4 r = *(const float4*)(ar + lane * 4);
  float sl = f.x * a.x + f.y * a.y + f.z * a.z + f.w * a.w;
  float sr = f.x * r.x + f.y * r.y + f.z * r.z + f.w * r.w;
#pragma unroll
  for (int m = 1; m < 16; m <<= 1) {
    sl += __shfl_xor(sl, m);
    sr += __shfl_xor(sr, m);
  }
  if ((lane & 15) == 0) {
    el[(size_t)node * 4 + (lane >> 4)] = sl;
    er[(size_t)node * 4 + (lane >> 4)] = sr;
  }
}

// ---------- el/er row-dots, layer 2 (H=1, D=64) ----------
__launch_bounds__(256)
__global__ void rowdot2_k(const float* __restrict__ ft, const float* __restrict__ al,
                          const float* __restrict__ ar, float* __restrict__ el,
                          float* __restrict__ er) {
  int node = blockIdx.x * 4 + (threadIdx.x >> 6);
  int lane = threadIdx.x & 63;
  if (node >= N_NODES) return;
  float f = ft[(size_t)node * 64 + lane];
  float sl = f * al[lane];
  float sr = f * ar[lane];
#pragma unroll
  for (int m = 1; m < 64; m <<= 1) {
    sl += __shfl_xor(sl, m);
    sr += __shfl_xor(sr, m);
  }
  if (lane == 0) {
    el[node] = sl;
    er[node] = sr;
  }
}

// ---------- layer-1 softmax passes (4 heads) ----------
__launch_bounds__(256)
__global__ void edge_max1_k(const int* __restrict__ src, const int* __restrict__ dst,
                            const float* __restrict__ el, const float* __restrict__ er,
                            unsigned* __restrict__ emax) {
  int e = blockIdx.x * 256 + threadIdx.x;
  if (e >= N_EDGES) return;
  int s = src[e], d = dst[e];
  float4 l = *(const float4*)(el + (size_t)s * 4);
  float4 r = *(const float4*)(er + (size_t)d * 4);
  unsigned* p = emax + (size_t)d * 4;
  atomicMax(p + 0, enc_f(leaky(l.x + r.x)));
  atomicMax(p + 1, enc_f(leaky(l.y + r.y)));
  atomicMax(p + 2, enc_f(leaky(l.z + r.z)));
  atomicMax(p + 3, enc_f(leaky(l.w + r.w)));
}

__launch_bounds__(256)
__global__ void edge_expsum1_k(const int* __restrict__ src, const int* __restrict__ dst,
                               const float* __restrict__ el, const float* __restrict__ er,
                               const unsigned* __restrict__ emax, float* __restrict__ denom) {
  int e = blockIdx.x * 256 + threadIdx.x;
  if (e >= N_EDGES) return;
  int s = src[e], d = dst[e];
  float4 l = *(const float4*)(el + (size_t)s * 4);
  float4 r = *(const float4*)(er + (size_t)d * 4);
  uint4 m = *(const uint4*)(emax + (size_t)d * 4);
  float* p = denom + (size_t)d * 4;
  atomicAdd(p + 0, expf(leaky(l.x + r.x) - dec_f(m.x)));
  atomicAdd(p + 1, expf(leaky(l.y + r.y) - dec_f(m.y)));
  atomicAdd(p + 2, expf(leaky(l.z + r.z) - dec_f(m.z)));
  atomicAdd(p + 3, expf(leaky(l.w + r.w) - dec_f(m.w)));
}

// one wave per edge; lane covers 4 consecutive of 256 feature channels.
__launch_bounds__(256)
__global__ void edge_agg1_k(const int* __restrict__ src, const int* __restrict__ dst,
                            const float* __restrict__ el, const float* __restrict__ er,
                            const unsigned* __restrict__ emax, const float* __restrict__ denom,
                            const float* __restrict__ ft, float* __restrict__ h1) {
  int e = blockIdx.x * 4 + (threadIdx.x >> 6);
  int lane = threadIdx.x & 63;
  if (e >= N_EDGES) return;
  int s = src[e], d = dst[e];
  float4 l = *(const float4*)(el + (size_t)s * 4);
  float4 r = *(const float4*)(er + (size_t)d * 4);
  uint4 m = *(const uint4*)(emax + (size_t)d * 4);
  float4 dn = *(const float4*)(denom + (size_t)d * 4);
  float a4[4];
  a4[0] = expf(leaky(l.x + r.x) - dec_f(m.x)) / dn.x;
  a4[1] = expf(leaky(l.y + r.y) - dec_f(m.y)) / dn.y;
  a4[2] = expf(leaky(l.z + r.z) - dec_f(m.z)) / dn.z;
  a4[3] = expf(leaky(l.w + r.w) - dec_f(m.w)) / dn.w;
  float a = a4[lane >> 4];
  float4 f = *(const float4*)(ft + (size_t)s * 256 + lane * 4);
  float* o = h1 + (size_t)d * 256 + lane * 4;
  atomicAdd(o + 0, f.x * a);
  atomicAdd(o + 1, f.y * a);
  atomicAdd(o + 2, f.z * a);
  atomicAdd(o + 3, f.w * a);
}

// ---------- bias + ELU on layer-1 output ----------
__launch_bounds__(256)
__global__ void bias_elu_k(float* __restrict__ h, const float* __restrict__ bias) {
  size_t i = ((size_t)blockIdx.x * 256 + threadIdx.x) * 4;
  if (i >= (size_t)N_NODES * 256) return;
  float4 v = *(float4*)(h + i);
  int c = (int)(i & 255);
  v.x += bias[c + 0];
  v.y += bias[c + 1];
  v.z += bias[c + 2];
  v.w += bias[c + 3];
  v.x = v.x > 0.f ? v.x : expm1f(v.x);
  v.y = v.y > 0.f ? v.y : expm1f(v.y);
  v.z = v.z > 0.f ? v.z : expm1f(v.z);
  v.w = v.w > 0.f ? v.w : expm1f(v.w);
  *(float4*)(h + i) = v;
}

// ---------- layer-2 softmax passes (1 head) ----------
__launch_bounds__(256)
__global__ void edge_max2_k(const int* __restrict__ src, const int* __restrict__ dst,
                            const float* __restrict__ el, const float* __restrict__ er,
                            unsigned* __restrict__ emax) {
  int e = blockIdx.x * 256 + threadIdx.x;
  if (e >= N_EDGES) return;
  int s = src[e], d = dst[e];
  atomicMax(emax + d, enc_f(leaky(el[s] + er[d])));
}

__launch_bounds__(256)
__global__ void edge_expsum2_k(const int* __restrict__ src, const int* __restrict__ dst,
                               const float* __restrict__ el, const float* __restrict__ er,
                               const unsigned* __restrict__ emax, float* __restrict__ denom) {
  int e = blockIdx.x * 256 + threadIdx.x;
  if (e >= N_EDGES) return;
  int s = src[e], d = dst[e];
  atomicAdd(denom + d, expf(leaky(el[s] + er[d]) - dec_f(emax[d])));
}

// one wave per edge; lane covers 1 of 64 channels; accumulates into d_out.
__launch_bounds__(256)
__global__ void edge_agg2_k(const int* __restrict__ src, const int* __restrict__ dst,
                            const float* __restrict__ el, const float* __restrict__ er,
                            const unsigned* __restrict__ emax, const float* __restrict__ denom,
                            const float* __restrict__ ft, float* __restrict__ out) {
  int e = blockIdx.x * 4 + (threadIdx.x >> 6);
  int lane = threadIdx.x & 63;
  if (e >= N_EDGES) return;
  int s = src[e], d = dst[e];
  float a = expf(leaky(el[s] + er[d]) - dec_f(emax[d])) / denom[d];
  atomicAdd(out + (size_t)d * 64 + lane, ft[(size_t)s * 64 + lane] * a);
}

// ---------- launch ----------
extern "C" void kernel_launch(void* const* d_in, const int* in_sizes, int n_in,
                              void* d_out, int out_size, void* d_ws, size_t ws_size,
                              hipStream_t stream) {
  const float* feat  = (const float*)d_in[0];
  const int*   src   = (const int*)d_in[1];
  const int*   dst   = (const int*)d_in[2];
  const float* W1    = (const float*)d_in[3];
  const float* al1   = (const float*)d_in[4];
  const float* ar1   = (const float*)d_in[5];
  const float* b1    = (const float*)d_in[6];
  const float* W2    = (const float*)d_in[7];
  const float* al2   = (const float*)d_in[8];
  const float* ar2   = (const float*)d_in[9];
  const float* b2    = (const float*)d_in[10];
  const float* resW2 = (const float*)d_in[11];
  float* out = (float*)d_out;

  // workspace layout (floats). zero-init region [h1 .. emax2] is contiguous.
  float* ws = (float*)d_ws;
  float* ft1 = ws;                                        // 12.8M
  float* h1 = ft1 + (size_t)N_NODES * 256;                // 12.8M (zero)
  float* denom1 = h1 + (size_t)N_NODES * 256;             // 200K (zero)
  unsigned* emax1 = (unsigned*)(denom1 + N_NODES * 4);    // 200K (zero = -inf-encoded floor)
  float* denom2 = (float*)(emax1 + N_NODES * 4);          // 50K (zero)
  unsigned* emax2 = (unsigned*)(denom2 + N_NODES);        // 50K (zero)
  float* ft2 = (float*)(emax2 + N_NODES);                 // 3.2M
  float* el1 = ft2 + (size_t)N_NODES * 64;                // 200K
  float* er1 = el1 + (size_t)N_NODES * 4;                 // 200K
  float* el2 = er1 + (size_t)N_NODES * 4;                 // 50K
  float* er2 = el2 + N_NODES;                             // 50K

  size_t zero_floats = (size_t)N_NODES * 256 + (size_t)N_NODES * 4 * 2 + (size_t)N_NODES * 2;
  hipMemsetAsync(h1, 0, zero_floats * sizeof(float), stream);

  dim3 blk(256);

  // layer 1
  sgemm_k<false><<<dim3(782, 4), blk, 0, stream>>>(feat, W1, nullptr, ft1, N_NODES, 256, 256);
  rowdot1_k<<<12500, blk, 0, stream>>>(ft1, al1, ar1, el1, er1);
  edge_max1_k<<<3125, blk, 0, stream>>>(src, dst, el1, er1, emax1);
  edge_expsum1_k<<<3125, blk, 0, stream>>>(src, dst, el1, er1, emax1, denom1);
  edge_agg1_k<<<200000, blk, 0, stream>>>(src, dst, el1, er1, emax1, denom1, ft1, h1);
  bias_elu_k<<<12500, blk, 0, stream>>>(h1, b1);

  // layer 2
  sgemm_k<false><<<dim3(782, 1), blk, 0, stream>>>(h1, W2, nullptr, ft2, N_NODES, 256, 64);
  sgemm_k<true><<<dim3(782, 1), blk, 0, stream>>>(h1, resW2, b2, out, N_NODES, 256, 64);
  rowdot2_k<<<12500, blk, 0, stream>>>(ft2, al2, ar2, el2, er2);
  edge_max2_k<<<3125, blk, 0, stream>>>(src, dst, el2, er2, emax2);
  edge_expsum2_k<<<3125, blk, 0, stream>>>(src, dst, el2, er2, emax2, denom2);
  edge_agg2_k<<<200000, blk, 0, stream>>>(src, dst, el2, er2, emax2, denom2, ft2, out);
}

// Round 2
// 843.110 us; speedup vs baseline: 4.2020x; 4.2020x over previous
//
#include <hip/hip_runtime.h>
#include <math.h>

#define N_NODES 50000
#define N_EDGES 800000

__device__ __forceinline__ float leaky(float x) { return x >= 0.f ? x : 0.2f * x; }

// ---------- fp32 tiled GEMM: C(MxN) = A(MxK) @ B(KxN) [+ bias] ----------
// 64x64 tile, BK=16, 256 threads, 4x4 microtile per thread.
template <bool ADD_BIAS>
__launch_bounds__(256)
__global__ void sgemm_k(const float* __restrict__ A, const float* __restrict__ B,
                        const float* __restrict__ bias, float* __restrict__ C,
                        int M, int K, int N) {
  __shared__ float As[16][68];
  __shared__ float Bs[16][64];
  const int tid = threadIdx.x;
  const int bm0 = blockIdx.x * 64;
  const int bn0 = blockIdx.y * 64;
  const int tm0 = (tid >> 4) * 4;
  const int tn0 = (tid & 15) * 4;
  const int am = tid >> 2;
  const int ak = (tid & 3) * 4;
  const int bk = tid >> 4;
  const int bn = (tid & 15) * 4;
  float acc[4][4] = {{0.f, 0.f, 0.f, 0.f}};

  for (int k0 = 0; k0 < K; k0 += 16) {
    float4 av = make_float4(0.f, 0.f, 0.f, 0.f);
    if (bm0 + am < M) av = *(const float4*)(A + (size_t)(bm0 + am) * K + k0 + ak);
    As[ak + 0][am] = av.x;
    As[ak + 1][am] = av.y;
    As[ak + 2][am] = av.z;
    As[ak + 3][am] = av.w;
    *(float4*)&Bs[bk][bn] = *(const float4*)(B + (size_t)(k0 + bk) * N + bn0 + bn);
    __syncthreads();
#pragma unroll
    for (int k = 0; k < 16; ++k) {
      float4 a = *(float4*)&As[k][tm0];
      float4 b = *(float4*)&Bs[k][tn0];
      acc[0][0] += a.x * b.x; acc[0][1] += a.x * b.y; acc[0][2] += a.x * b.z; acc[0][3] += a.x * b.w;
      acc[1][0] += a.y * b.x; acc[1][1] += a.y * b.y; acc[1][2] += a.y * b.z; acc[1][3] += a.y * b.w;
      acc[2][0] += a.z * b.x; acc[2][1] += a.z * b.y; acc[2][2] += a.z * b.z; acc[2][3] += a.z * b.w;
      acc[3][0] += a.w * b.x; acc[3][1] += a.w * b.y; acc[3][2] += a.w * b.z; acc[3][3] += a.w * b.w;
    }
    __syncthreads();
  }
#pragma unroll
  for (int i = 0; i < 4; ++i) {
    int m = bm0 + tm0 + i;
    if (m >= M) break;
    float4 v = make_float4(acc[i][0], acc[i][1], acc[i][2], acc[i][3]);
    if (ADD_BIAS) {
      v.x += bias[bn0 + tn0 + 0];
      v.y += bias[bn0 + tn0 + 1];
      v.z += bias[bn0 + tn0 + 2];
      v.w += bias[bn0 + tn0 + 3];
    }
    *(float4*)(C + (size_t)m * N + bn0 + tn0) = v;
  }
}

// ---------- CSR build: histogram, scan, scatter ----------
__launch_bounds__(256)
__global__ void hist_k(const int* __restrict__ dst, int* __restrict__ cnt) {
  int e = blockIdx.x * 256 + threadIdx.x;
  if (e < N_EDGES) atomicAdd(cnt + dst[e], 1);
}

// single-block exclusive scan over N_NODES counts -> off[N+1], cursor[N]
__launch_bounds__(1024)
__global__ void scan_k(const int* __restrict__ cnt, int* __restrict__ off,
                       int* __restrict__ cursor) {
  __shared__ int buf[1024];
  __shared__ int s_carry;
  if (threadIdx.x == 0) { s_carry = 0; off[0] = 0; }
  __syncthreads();
  for (int base = 0; base < N_NODES; base += 1024) {
    int i = base + threadIdx.x;
    int v = (i < N_NODES) ? cnt[i] : 0;
    buf[threadIdx.x] = v;
    __syncthreads();
#pragma unroll
    for (int s = 1; s < 1024; s <<= 1) {
      int t = (threadIdx.x >= s) ? buf[threadIdx.x - s] : 0;
      __syncthreads();
      buf[threadIdx.x] += t;
      __syncthreads();
    }
    int carry = s_carry;
    __syncthreads();
    if (threadIdx.x == 1023) s_carry = carry + buf[1023];
    if (i < N_NODES) {
      int inc = carry + buf[threadIdx.x];
      off[i + 1] = inc;
      cursor[i] = inc - v;
    }
    __syncthreads();
  }
}

__launch_bounds__(256)
__global__ void scatter_k(const int* __restrict__ dst, int* __restrict__ cursor,
                          int* __restrict__ eidx) {
  int e = blockIdx.x * 256 + threadIdx.x;
  if (e >= N_EDGES) return;
  int p = atomicAdd(cursor + dst[e], 1);
  eidx[p] = e;
}

// ---------- el/er row-dots, layer 1 (H=4, D=64) ----------
__launch_bounds__(256)
__global__ void rowdot1_k(const float* __restrict__ ft, const float* __restrict__ al,
                          const float* __restrict__ ar, float* __restrict__ el,
                          float* __restrict__ er) {
  int node = blockIdx.x * 4 + (threadIdx.x >> 6);
  int lane = threadIdx.x & 63;
  if (node >= N_NODES) return;
  float4 f = *(const float4*)(ft + (size_t)node * 256 + lane * 4);
  float4 a = *(const float4*)(al + lane * 4);
  float4 r = *(const float4*)(ar + lane * 4);
  float sl = f.x * a.x + f.y * a.y + f.z * a.z + f.w * a.w;
  float sr = f.x * r.x + f.y * r.y + f.z * r.z + f.w * r.w;
#pragma unroll
  for (int m = 1; m < 16; m <<= 1) {
    sl += __shfl_xor(sl, m);
    sr += __shfl_xor(sr, m);
  }
  if ((lane & 15) == 0) {
    el[(size_t)node * 4 + (lane >> 4)] = sl;
    er[(size_t)node * 4 + (lane >> 4)] = sr;
  }
}

// ---------- el/er row-dots, layer 2 (H=1, D=64) ----------
__launch_bounds__(256)
__global__ void rowdot2_k(const float* __restrict__ ft, const float* __restrict__ al,
                          const float* __restrict__ ar, float* __restrict__ el,
                          float* __restrict__ er) {
  int node = blockIdx.x * 4 + (threadIdx.x >> 6);
  int lane = threadIdx.x & 63;
  if (node >= N_NODES) return;
  float f = ft[(size_t)node * 64 + lane];
  float sl = f * al[lane];
  float sr = f * ar[lane];
#pragma unroll
  for (int m = 1; m < 64; m <<= 1) {
    sl += __shfl_xor(sl, m);
    sr += __shfl_xor(sr, m);
  }
  if (lane == 0) {
    el[node] = sl;
    er[node] = sr;
  }
}

// ---------- layer-1 fused softmax+aggregate+bias+ELU, owner-computes ----------
// one wave per dst node; lane holds channels lane*4..lane*4+3; head = lane/16.
__launch_bounds__(256)
__global__ void agg1_k(const int* __restrict__ eidx, const int* __restrict__ off,
                       const int* __restrict__ src, const float* __restrict__ el,
                       const float* __restrict__ er, const float* __restrict__ ft,
                       const float* __restrict__ bias, float* __restrict__ h1) {
  int node = blockIdx.x * 4 + (threadIdx.x >> 6);
  int lane = threadIdx.x & 63;
  if (node >= N_NODES) return;
  int beg = off[node], end = off[node + 1];
  int h = lane >> 4;
  float erh = er[(size_t)node * 4 + h];
  float m = -INFINITY;
  for (int i = beg; i < end; ++i) {
    int s = src[eidx[i]];
    m = fmaxf(m, leaky(el[(size_t)s * 4 + h] + erh));
  }
  float denom = 0.f;
  float4 acc = make_float4(0.f, 0.f, 0.f, 0.f);
  for (int i = beg; i < end; ++i) {
    int s = src[eidx[i]];
    float w = expf(leaky(el[(size_t)s * 4 + h] + erh) - m);
    denom += w;
    float4 f = *(const float4*)(ft + (size_t)s * 256 + lane * 4);
    acc.x += w * f.x;
    acc.y += w * f.y;
    acc.z += w * f.z;
    acc.w += w * f.w;
  }
  float inv = (end > beg) ? 1.f / denom : 0.f;
  float4 b = *(const float4*)(bias + lane * 4);
  float4 v;
  v.x = acc.x * inv + b.x;
  v.y = acc.y * inv + b.y;
  v.z = acc.z * inv + b.z;
  v.w = acc.w * inv + b.w;
  v.x = v.x > 0.f ? v.x : expm1f(v.x);
  v.y = v.y > 0.f ? v.y : expm1f(v.y);
  v.z = v.z > 0.f ? v.z : expm1f(v.z);
  v.w = v.w > 0.f ? v.w : expm1f(v.w);
  *(float4*)(h1 + (size_t)node * 256 + lane * 4) = v;
}

// ---------- layer-2 fused softmax+aggregate+residual, owner-computes ----------
// one wave per dst node; lane holds 1 of 64 channels. out already holds
// h1 @ resW2 + b2; we add rst in place (single owner, no atomics).
__launch_bounds__(256)
__global__ void agg2_k(const int* __restrict__ eidx, const int* __restrict__ off,
                       const int* __restrict__ src, const float* __restrict__ el,
                       const float* __restrict__ er, const float* __restrict__ ft,
                       float* __restrict__ out) {
  int node = blockIdx.x * 4 + (threadIdx.x >> 6);
  int lane = threadIdx.x & 63;
  if (node >= N_NODES) return;
  int beg = off[node], end = off[node + 1];
  float erd = er[node];
  float m = -INFINITY;
  for (int i = beg; i < end; ++i) {
    int s = src[eidx[i]];
    m = fmaxf(m, leaky(el[s] + erd));
  }
  float denom = 0.f, acc = 0.f;
  for (int i = beg; i < end; ++i) {
    int s = src[eidx[i]];
    float w = expf(leaky(el[s] + erd) - m);
    denom += w;
    acc += w * ft[(size_t)s * 64 + lane];
  }
  float r = (end > beg) ? acc / denom : 0.f;
  out[(size_t)node * 64 + lane] += r;
}

// ---------- launch ----------
extern "C" void kernel_launch(void* const* d_in, const int* in_sizes, int n_in,
                              void* d_out, int out_size, void* d_ws, size_t ws_size,
                              hipStream_t stream) {
  const float* feat  = (const float*)d_in[0];
  const int*   src   = (const int*)d_in[1];
  const int*   dst   = (const int*)d_in[2];
  const float* W1    = (const float*)d_in[3];
  const float* al1   = (const float*)d_in[4];
  const float* ar1   = (const float*)d_in[5];
  const float* b1    = (const float*)d_in[6];
  const float* W2    = (const float*)d_in[7];
  const float* al2   = (const float*)d_in[8];
  const float* ar2   = (const float*)d_in[9];
  const float* b2    = (const float*)d_in[10];
  const float* resW2 = (const float*)d_in[11];
  float* out = (float*)d_out;

  // workspace layout (floats)
  float* ws = (float*)d_ws;
  float* ft1 = ws;                                        // 50000*256
  float* h1 = ft1 + (size_t)N_NODES * 256;                // 50000*256
  float* ft2 = h1 + (size_t)N_NODES * 256;                // 50000*64
  float* el1 = ft2 + (size_t)N_NODES * 64;                // 50000*4
  float* er1 = el1 + (size_t)N_NODES * 4;                 // 50000*4
  float* el2 = er1 + (size_t)N_NODES * 4;                 // 50000
  float* er2 = el2 + N_NODES;                             // 50000
  int* cnt = (int*)(er2 + N_NODES);                       // 50000 (zero)
  int* off = cnt + N_NODES;                               // 50001
  int* cursor = off + N_NODES + 1;                        // 50000
  int* eidx = cursor + N_NODES;                           // 800000

  hipMemsetAsync(cnt, 0, (size_t)N_NODES * sizeof(int), stream);

  dim3 blk(256);

  // CSR by dst (shared by both layers)
  hist_k<<<3125, blk, 0, stream>>>(dst, cnt);
  scan_k<<<1, 1024, 0, stream>>>(cnt, off, cursor);
  scatter_k<<<3125, blk, 0, stream>>>(dst, cursor, eidx);

  // layer 1
  sgemm_k<false><<<dim3(782, 4), blk, 0, stream>>>(feat, W1, nullptr, ft1, N_NODES, 256, 256);
  rowdot1_k<<<12500, blk, 0, stream>>>(ft1, al1, ar1, el1, er1);
  agg1_k<<<12500, blk, 0, stream>>>(eidx, off, src, el1, er1, ft1, b1, h1);

  // layer 2
  sgemm_k<false><<<dim3(782, 1), blk, 0, stream>>>(h1, W2, nullptr, ft2, N_NODES, 256, 64);
  sgemm_k<true><<<dim3(782, 1), blk, 0, stream>>>(h1, resW2, b2, out, N_NODES, 256, 64);
  rowdot2_k<<<12500, blk, 0, stream>>>(ft2, al2, ar2, el2, er2);
  agg2_k<<<12500, blk, 0, stream>>>(eidx, off, src, el2, er2, ft2, out);
}

// Round 3
// 704.762 us; speedup vs baseline: 5.0269x; 1.1963x over previous
//
#include <hip/hip_runtime.h>
#include <math.h>

#define N_NODES 50000
#define N_EDGES 800000

typedef __attribute__((ext_vector_type(8))) short bf16x8;
typedef __attribute__((ext_vector_type(4))) float f32x4;

__device__ __forceinline__ float leaky(float x) { return x >= 0.f ? x : 0.2f * x; }
__device__ __forceinline__ unsigned short f2bf(float f) {
  unsigned u = __float_as_uint(f);
  return (unsigned short)((u + 0x7fffu + ((u >> 16) & 1u)) >> 16);
}
__device__ __forceinline__ float bflo(unsigned u) { return __uint_as_float(u << 16); }
__device__ __forceinline__ float bfhi(unsigned u) { return __uint_as_float(u & 0xffff0000u); }
__device__ __forceinline__ unsigned pack2(float a, float b) {
  return (unsigned)f2bf(a) | ((unsigned)f2bf(b) << 16);
}

// ---------- weight pack: fp32 (KxN) -> bf16 (N-major, K contiguous) ----------
__launch_bounds__(256)
__global__ void packW1_k(const float* __restrict__ W, short* __restrict__ Wt) {
  int idx = blockIdx.x * 256 + threadIdx.x;  // 256*256
  int n = idx >> 8, k = idx & 255;
  Wt[idx] = (short)f2bf(W[(size_t)k * 256 + n]);
}
// cols 0..63 from W2 (256x64), cols 64..127 from resW2 (256x64)
__launch_bounds__(256)
__global__ void packW2_k(const float* __restrict__ W2, const float* __restrict__ resW2,
                         short* __restrict__ Wt) {
  int idx = blockIdx.x * 256 + threadIdx.x;  // 128*256
  int n = idx >> 8, k = idx & 255;
  float v = (n < 64) ? W2[(size_t)k * 64 + n] : resW2[(size_t)k * 64 + (n - 64)];
  Wt[idx] = (short)f2bf(v);
}

// ---------- bf16 MFMA GEMM: C(MxN) = A(MxK) @ B(KxN), Bt is N-major bf16 ----------
// 128x128 tile, BK=32, 256 thr = 4 waves (2x2 of 64x64), 4x4 frags of 16x16x32.
// MODE 0: store C as bf16 to Cb (ldc = N).
// MODE 1: N=128; cols<64 -> Cb bf16 (ld 64); cols>=64 -> Cf fp32 = acc + bias[col-64].
template <bool A_BF16, int MODE>
__launch_bounds__(256)
__global__ void mfma_gemm_k(const void* __restrict__ Ap, const short* __restrict__ Bt,
                            const float* __restrict__ bias, short* __restrict__ Cb,
                            float* __restrict__ Cf, int M, int K, int N) {
  __shared__ short As[4][128][8];  // [k-quad][row][k-in-quad]
  __shared__ short Bs[4][128][8];  // [k-quad][col][k-in-quad]
  const int tid = threadIdx.x;
  const int bm0 = blockIdx.x * 128, bn0 = blockIdx.y * 128;
  const int wave = tid >> 6, lane = tid & 63;
  const int wm = (wave & 1) * 64, wn = (wave >> 1) * 64;
  const int q = lane >> 4, r16 = lane & 15;
  const int srow = tid >> 1, sk = (tid & 1) * 16, sq = (tid & 1) * 2;
  f32x4 acc[4][4] = {};

  for (int k0 = 0; k0 < K; k0 += 32) {
    if (A_BF16) {
      const short* A = (const short*)Ap;
      uint4 v0 = {0, 0, 0, 0}, v1 = {0, 0, 0, 0};
      if (bm0 + srow < M) {
        const uint4* p = (const uint4*)(A + (size_t)(bm0 + srow) * K + k0 + sk);
        v0 = p[0];
        v1 = p[1];
      }
      *(uint4*)&As[sq][srow][0] = v0;
      *(uint4*)&As[sq + 1][srow][0] = v1;
    } else {
      const float* A = (const float*)Ap;
      float4 f0 = {0, 0, 0, 0}, f1 = f0, f2 = f0, f3 = f0;
      if (bm0 + srow < M) {
        const float4* p = (const float4*)(A + (size_t)(bm0 + srow) * K + k0 + sk);
        f0 = p[0];
        f1 = p[1];
        f2 = p[2];
        f3 = p[3];
      }
      uint4 v0, v1;
      v0.x = pack2(f0.x, f0.y); v0.y = pack2(f0.z, f0.w);
      v0.z = pack2(f1.x, f1.y); v0.w = pack2(f1.z, f1.w);
      v1.x = pack2(f2.x, f2.y); v1.y = pack2(f2.z, f2.w);
      v1.z = pack2(f3.x, f3.y); v1.w = pack2(f3.z, f3.w);
      *(uint4*)&As[sq][srow][0] = v0;
      *(uint4*)&As[sq + 1][srow][0] = v1;
    }
    {
      const uint4* p = (const uint4*)(Bt + (size_t)(bn0 + srow) * K + k0 + sk);
      *(uint4*)&Bs[sq][srow][0] = p[0];
      *(uint4*)&Bs[sq + 1][srow][0] = p[1];
    }
    __syncthreads();
    bf16x8 af[4], bfr[4];
#pragma unroll
    for (int i = 0; i < 4; ++i) af[i] = *(const bf16x8*)&As[q][wm + i * 16 + r16][0];
#pragma unroll
    for (int j = 0; j < 4; ++j) bfr[j] = *(const bf16x8*)&Bs[q][wn + j * 16 + r16][0];
#pragma unroll
    for (int i = 0; i < 4; ++i)
#pragma unroll
      for (int j = 0; j < 4; ++j)
        acc[i][j] = __builtin_amdgcn_mfma_f32_16x16x32_bf16(af[i], bfr[j], acc[i][j], 0, 0, 0);
    __syncthreads();
  }

#pragma unroll
  for (int i = 0; i < 4; ++i) {
#pragma unroll
    for (int reg = 0; reg < 4; ++reg) {
      int row_g = bm0 + wm + i * 16 + q * 4 + reg;
      if (row_g >= M) continue;
#pragma unroll
      for (int j = 0; j < 4; ++j) {
        int col_g = bn0 + wn + j * 16 + r16;
        float v = acc[i][j][reg];
        if (MODE == 0) {
          Cb[(size_t)row_g * N + col_g] = (short)f2bf(v);
        } else {
          if (col_g < 64)
            Cb[(size_t)row_g * 64 + col_g] = (short)f2bf(v);
          else
            Cf[(size_t)row_g * 64 + (col_g - 64)] = v + bias[col_g - 64];
        }
      }
    }
  }
}

// ---------- CSR build: histogram, scan, scatter ----------
__launch_bounds__(256)
__global__ void hist_k(const int* __restrict__ dst, int* __restrict__ cnt) {
  int e = blockIdx.x * 256 + threadIdx.x;
  if (e < N_EDGES) atomicAdd(cnt + dst[e], 1);
}

__launch_bounds__(1024)
__global__ void scan_k(const int* __restrict__ cnt, int* __restrict__ off,
                       int* __restrict__ cursor) {
  __shared__ int buf[1024];
  __shared__ int s_carry;
  if (threadIdx.x == 0) { s_carry = 0; off[0] = 0; }
  __syncthreads();
  for (int base = 0; base < N_NODES; base += 1024) {
    int i = base + threadIdx.x;
    int v = (i < N_NODES) ? cnt[i] : 0;
    buf[threadIdx.x] = v;
    __syncthreads();
#pragma unroll
    for (int s = 1; s < 1024; s <<= 1) {
      int t = (threadIdx.x >= s) ? buf[threadIdx.x - s] : 0;
      __syncthreads();
      buf[threadIdx.x] += t;
      __syncthreads();
    }
    int carry = s_carry;
    __syncthreads();
    if (threadIdx.x == 1023) s_carry = carry + buf[1023];
    if (i < N_NODES) {
      int inc = carry + buf[threadIdx.x];
      off[i + 1] = inc;
      cursor[i] = inc - v;
    }
    __syncthreads();
  }
}

__launch_bounds__(256)
__global__ void scatter_k(const int* __restrict__ dst, int* __restrict__ cursor,
                          int* __restrict__ eidx) {
  int e = blockIdx.x * 256 + threadIdx.x;
  if (e >= N_EDGES) return;
  int p = atomicAdd(cursor + dst[e], 1);
  eidx[p] = e;
}

// ---------- el/er row-dots, layer 1 (H=4, D=64), bf16 features ----------
__launch_bounds__(256)
__global__ void rowdot1_k(const short* __restrict__ ft, const float* __restrict__ al,
                          const float* __restrict__ ar, float* __restrict__ el,
                          float* __restrict__ er) {
  int node = blockIdx.x * 4 + (threadIdx.x >> 6);
  int lane = threadIdx.x & 63;
  if (node >= N_NODES) return;
  uint2 u = *(const uint2*)(ft + (size_t)node * 256 + lane * 4);
  float x0 = bflo(u.x), x1 = bfhi(u.x), x2 = bflo(u.y), x3 = bfhi(u.y);
  float4 a = *(const float4*)(al + lane * 4);
  float4 r = *(const float4*)(ar + lane * 4);
  float sl = x0 * a.x + x1 * a.y + x2 * a.z + x3 * a.w;
  float sr = x0 * r.x + x1 * r.y + x2 * r.z + x3 * r.w;
#pragma unroll
  for (int m = 1; m < 16; m <<= 1) {
    sl += __shfl_xor(sl, m);
    sr += __shfl_xor(sr, m);
  }
  if ((lane & 15) == 0) {
    el[(size_t)node * 4 + (lane >> 4)] = sl;
    er[(size_t)node * 4 + (lane >> 4)] = sr;
  }
}

// ---------- el/er row-dots, layer 2 (H=1, D=64), bf16 features ----------
__launch_bounds__(256)
__global__ void rowdot2_k(const short* __restrict__ ft, const float* __restrict__ al,
                          const float* __restrict__ ar, float* __restrict__ el,
                          float* __restrict__ er) {
  int node = blockIdx.x * 4 + (threadIdx.x >> 6);
  int lane = threadIdx.x & 63;
  if (node >= N_NODES) return;
  float f = bflo((unsigned)(unsigned short)ft[(size_t)node * 64 + lane]);
  float sl = f * al[lane];
  float sr = f * ar[lane];
#pragma unroll
  for (int m = 1; m < 64; m <<= 1) {
    sl += __shfl_xor(sl, m);
    sr += __shfl_xor(sr, m);
  }
  if (lane == 0) {
    el[node] = sl;
    er[node] = sr;
  }
}

// ---------- layer-1 fused softmax+aggregate+bias+ELU (bf16 in/out) ----------
__launch_bounds__(256)
__global__ void agg1_k(const int* __restrict__ eidx, const int* __restrict__ off,
                       const int* __restrict__ src, const float* __restrict__ el,
                       const float* __restrict__ er, const short* __restrict__ ft,
                       const float* __restrict__ bias, short* __restrict__ h1) {
  int node = blockIdx.x * 4 + (threadIdx.x >> 6);
  int lane = threadIdx.x & 63;
  if (node >= N_NODES) return;
  int beg = off[node], end = off[node + 1];
  int h = lane >> 4;
  float erh = er[(size_t)node * 4 + h];
  float m = -INFINITY;
  for (int i = beg; i < end; ++i) {
    int s = src[eidx[i]];
    m = fmaxf(m, leaky(el[(size_t)s * 4 + h] + erh));
  }
  float denom = 0.f;
  float4 acc = make_float4(0.f, 0.f, 0.f, 0.f);
  for (int i = beg; i < end; ++i) {
    int s = src[eidx[i]];
    float w = expf(leaky(el[(size_t)s * 4 + h] + erh) - m);
    denom += w;
    uint2 u = *(const uint2*)(ft + (size_t)s * 256 + lane * 4);
    acc.x += w * bflo(u.x);
    acc.y += w * bfhi(u.x);
    acc.z += w * bflo(u.y);
    acc.w += w * bfhi(u.y);
  }
  float inv = (end > beg) ? 1.f / denom : 0.f;
  float4 b = *(const float4*)(bias + lane * 4);
  float4 v;
  v.x = acc.x * inv + b.x;
  v.y = acc.y * inv + b.y;
  v.z = acc.z * inv + b.z;
  v.w = acc.w * inv + b.w;
  v.x = v.x > 0.f ? v.x : expm1f(v.x);
  v.y = v.y > 0.f ? v.y : expm1f(v.y);
  v.z = v.z > 0.f ? v.z : expm1f(v.z);
  v.w = v.w > 0.f ? v.w : expm1f(v.w);
  uint2 o;
  o.x = pack2(v.x, v.y);
  o.y = pack2(v.z, v.w);
  *(uint2*)(h1 + (size_t)node * 256 + lane * 4) = o;
}

// ---------- layer-2 fused softmax+aggregate+residual (bf16 gather) ----------
__launch_bounds__(256)
__global__ void agg2_k(const int* __restrict__ eidx, const int* __restrict__ off,
                       const int* __restrict__ src, const float* __restrict__ el,
                       const float* __restrict__ er, const short* __restrict__ ft,
                       float* __restrict__ out) {
  int node = blockIdx.x * 4 + (threadIdx.x >> 6);
  int lane = threadIdx.x & 63;
  if (node >= N_NODES) return;
  int beg = off[node], end = off[node + 1];
  float erd = er[node];
  float m = -INFINITY;
  for (int i = beg; i < end; ++i) {
    int s = src[eidx[i]];
    m = fmaxf(m, leaky(el[s] + erd));
  }
  float denom = 0.f, acc = 0.f;
  for (int i = beg; i < end; ++i) {
    int s = src[eidx[i]];
    float w = expf(leaky(el[s] + erd) - m);
    denom += w;
    acc += w * bflo((unsigned)(unsigned short)ft[(size_t)s * 64 + lane]);
  }
  float r = (end > beg) ? acc / denom : 0.f;
  out[(size_t)node * 64 + lane] += r;
}

// ---------- launch ----------
extern "C" void kernel_launch(void* const* d_in, const int* in_sizes, int n_in,
                              void* d_out, int out_size, void* d_ws, size_t ws_size,
                              hipStream_t stream) {
  const float* feat  = (const float*)d_in[0];
  const int*   src   = (const int*)d_in[1];
  const int*   dst   = (const int*)d_in[2];
  const float* W1    = (const float*)d_in[3];
  const float* al1   = (const float*)d_in[4];
  const float* ar1   = (const float*)d_in[5];
  const float* b1    = (const float*)d_in[6];
  const float* W2    = (const float*)d_in[7];
  const float* al2   = (const float*)d_in[8];
  const float* ar2   = (const float*)d_in[9];
  const float* b2    = (const float*)d_in[10];
  const float* resW2 = (const float*)d_in[11];
  float* out = (float*)d_out;

  char* p = (char*)d_ws;
  short* ft1b = (short*)p; p += (size_t)N_NODES * 256 * 2;
  short* h1b  = (short*)p; p += (size_t)N_NODES * 256 * 2;
  short* ft2b = (short*)p; p += (size_t)N_NODES * 64 * 2;
  short* Wt1  = (short*)p; p += 256 * 256 * 2;
  short* Wt2  = (short*)p; p += 128 * 256 * 2;
  float* el1  = (float*)p; p += (size_t)N_NODES * 4 * 4;
  float* er1  = (float*)p; p += (size_t)N_NODES * 4 * 4;
  float* el2  = (float*)p; p += (size_t)N_NODES * 4;
  float* er2  = (float*)p; p += (size_t)N_NODES * 4;
  int* cnt    = (int*)p;   p += (size_t)N_NODES * 4;
  int* off    = (int*)p;   p += (size_t)(N_NODES + 1) * 4;
  int* cursor = (int*)p;   p += (size_t)N_NODES * 4;
  int* eidx   = (int*)p;

  hipMemsetAsync(cnt, 0, (size_t)N_NODES * sizeof(int), stream);

  dim3 blk(256);

  // CSR by dst (shared by both layers)
  hist_k<<<3125, blk, 0, stream>>>(dst, cnt);
  scan_k<<<1, 1024, 0, stream>>>(cnt, off, cursor);
  scatter_k<<<3125, blk, 0, stream>>>(dst, cursor, eidx);

  // weight packs
  packW1_k<<<256, blk, 0, stream>>>(W1, Wt1);
  packW2_k<<<128, blk, 0, stream>>>(W2, resW2, Wt2);

  // layer 1: ft1 = feat @ W1 (bf16 out)
  mfma_gemm_k<false, 0><<<dim3(391, 2), blk, 0, stream>>>(feat, Wt1, nullptr, ft1b, nullptr,
                                                          N_NODES, 256, 256);
  rowdot1_k<<<12500, blk, 0, stream>>>(ft1b, al1, ar1, el1, er1);
  agg1_k<<<12500, blk, 0, stream>>>(eidx, off, src, el1, er1, ft1b, b1, h1b);

  // layer 2: [ft2 | res+b2] = h1 @ [W2 | resW2]
  mfma_gemm_k<true, 1><<<dim3(391, 1), blk, 0, stream>>>(h1b, Wt2, b2, ft2b, out,
                                                         N_NODES, 256, 128);
  rowdot2_k<<<12500, blk, 0, stream>>>(ft2b, al2, ar2, el2, er2);
  agg2_k<<<12500, blk, 0, stream>>>(eidx, off, src, el2, er2, ft2b, out);
}

// Round 4
// 423.881 us; speedup vs baseline: 8.3579x; 1.6626x over previous
//
#include <hip/hip_runtime.h>
#include <math.h>

#define N_NODES 50000
#define N_EDGES 800000
#define SCAN_BLK 49  // ceil(50000/1024)

typedef __attribute__((ext_vector_type(8))) short bf16x8;
typedef __attribute__((ext_vector_type(4))) float f32x4;

__device__ __forceinline__ float leaky(float x) { return x >= 0.f ? x : 0.2f * x; }
__device__ __forceinline__ unsigned short f2bf(float f) {
  unsigned u = __float_as_uint(f);
  return (unsigned short)((u + 0x7fffu + ((u >> 16) & 1u)) >> 16);
}
__device__ __forceinline__ float bflo(unsigned u) { return __uint_as_float(u << 16); }
__device__ __forceinline__ float bfhi(unsigned u) { return __uint_as_float(u & 0xffff0000u); }
__device__ __forceinline__ unsigned pack2(float a, float b) {
  return (unsigned)f2bf(a) | ((unsigned)f2bf(b) << 16);
}

// ---------- merged weight pack: W1 (256x256) then [W2|resW2] (256x128) ----------
__launch_bounds__(256)
__global__ void packW_k(const float* __restrict__ W1, const float* __restrict__ W2,
                        const float* __restrict__ resW2, short* __restrict__ Wt1,
                        short* __restrict__ Wt2) {
  int b = blockIdx.x;
  if (b < 256) {
    int idx = b * 256 + threadIdx.x;
    int n = idx >> 8, k = idx & 255;
    Wt1[idx] = (short)f2bf(W1[(size_t)k * 256 + n]);
  } else {
    int idx = (b - 256) * 256 + threadIdx.x;
    int n = idx >> 8, k = idx & 255;
    float v = (n < 64) ? W2[(size_t)k * 64 + n] : resW2[(size_t)k * 64 + (n - 64)];
    Wt2[idx] = (short)f2bf(v);
  }
}

// ---------- bf16 MFMA GEMM with fused el/er row-dot epilogue ----------
// 128x128 tile, BK=32, 256 thr = 4 waves (2x2 of 64x64), 4x4 frags of 16x16x32.
// MODE 0: C -> bf16 Cb (ldc=N); every wave covers one head's 64 cols -> el/er (N,4).
// MODE 1: N=128; cols<64 -> bf16 Cb (ld 64) + el/er (N,) from wn==0 waves;
//         cols>=64 -> fp32 Cf = acc + bias[col-64].
template <bool A_BF16, int MODE>
__launch_bounds__(256)
__global__ void mfma_gemm_k(const void* __restrict__ Ap, const short* __restrict__ Bt,
                            const float* __restrict__ bias, const float* __restrict__ al,
                            const float* __restrict__ ar, float* __restrict__ elp,
                            float* __restrict__ erp, short* __restrict__ Cb,
                            float* __restrict__ Cf, int M, int K, int N) {
  __shared__ short As[4][128][8];  // [k-quad][row][k-in-quad]
  __shared__ short Bs[4][128][8];  // [k-quad][col][k-in-quad]
  const int tid = threadIdx.x;
  const int bm0 = blockIdx.x * 128, bn0 = blockIdx.y * 128;
  const int wave = tid >> 6, lane = tid & 63;
  const int wm = (wave & 1) * 64, wn = (wave >> 1) * 64;
  const int q = lane >> 4, r16 = lane & 15;
  const int srow = tid >> 1, sk = (tid & 1) * 16, sq = (tid & 1) * 2;
  f32x4 acc[4][4] = {};

  for (int k0 = 0; k0 < K; k0 += 32) {
    if (A_BF16) {
      const short* A = (const short*)Ap;
      uint4 v0 = {0, 0, 0, 0}, v1 = {0, 0, 0, 0};
      if (bm0 + srow < M) {
        const uint4* p = (const uint4*)(A + (size_t)(bm0 + srow) * K + k0 + sk);
        v0 = p[0];
        v1 = p[1];
      }
      *(uint4*)&As[sq][srow][0] = v0;
      *(uint4*)&As[sq + 1][srow][0] = v1;
    } else {
      const float* A = (const float*)Ap;
      float4 f0 = {0, 0, 0, 0}, f1 = f0, f2 = f0, f3 = f0;
      if (bm0 + srow < M) {
        const float4* p = (const float4*)(A + (size_t)(bm0 + srow) * K + k0 + sk);
        f0 = p[0];
        f1 = p[1];
        f2 = p[2];
        f3 = p[3];
      }
      uint4 v0, v1;
      v0.x = pack2(f0.x, f0.y); v0.y = pack2(f0.z, f0.w);
      v0.z = pack2(f1.x, f1.y); v0.w = pack2(f1.z, f1.w);
      v1.x = pack2(f2.x, f2.y); v1.y = pack2(f2.z, f2.w);
      v1.z = pack2(f3.x, f3.y); v1.w = pack2(f3.z, f3.w);
      *(uint4*)&As[sq][srow][0] = v0;
      *(uint4*)&As[sq + 1][srow][0] = v1;
    }
    {
      const uint4* p = (const uint4*)(Bt + (size_t)(bn0 + srow) * K + k0 + sk);
      *(uint4*)&Bs[sq][srow][0] = p[0];
      *(uint4*)&Bs[sq + 1][srow][0] = p[1];
    }
    __syncthreads();
    bf16x8 af[4], bfr[4];
#pragma unroll
    for (int i = 0; i < 4; ++i) af[i] = *(const bf16x8*)&As[q][wm + i * 16 + r16][0];
#pragma unroll
    for (int j = 0; j < 4; ++j) bfr[j] = *(const bf16x8*)&Bs[q][wn + j * 16 + r16][0];
#pragma unroll
    for (int i = 0; i < 4; ++i)
#pragma unroll
      for (int j = 0; j < 4; ++j)
        acc[i][j] = __builtin_amdgcn_mfma_f32_16x16x32_bf16(af[i], bfr[j], acc[i][j], 0, 0, 0);
    __syncthreads();
  }

  // C store
#pragma unroll
  for (int i = 0; i < 4; ++i) {
#pragma unroll
    for (int reg = 0; reg < 4; ++reg) {
      int row_g = bm0 + wm + i * 16 + q * 4 + reg;
      if (row_g >= M) continue;
#pragma unroll
      for (int j = 0; j < 4; ++j) {
        int col_g = bn0 + wn + j * 16 + r16;
        float v = acc[i][j][reg];
        if (MODE == 0) {
          Cb[(size_t)row_g * N + col_g] = (short)f2bf(v);
        } else {
          if (col_g < 64)
            Cb[(size_t)row_g * 64 + col_g] = (short)f2bf(v);
          else
            Cf[(size_t)row_g * 64 + (col_g - 64)] = v + bias[col_g - 64];
        }
      }
    }
  }

  // fused el/er row-dot: this wave's 64 cols are exactly one head
  if (MODE == 0 || wn == 0) {
    const int head = (bn0 + wn) >> 6;
    float alv[4], arv[4];
#pragma unroll
    for (int j = 0; j < 4; ++j) {
      alv[j] = al[((MODE == 0) ? head * 64 : 0) + j * 16 + r16];
      arv[j] = ar[((MODE == 0) ? head * 64 : 0) + j * 16 + r16];
    }
#pragma unroll
    for (int i = 0; i < 4; ++i) {
#pragma unroll
      for (int reg = 0; reg < 4; ++reg) {
        float dl = acc[i][0][reg] * alv[0] + acc[i][1][reg] * alv[1] +
                   acc[i][2][reg] * alv[2] + acc[i][3][reg] * alv[3];
        float dr = acc[i][0][reg] * arv[0] + acc[i][1][reg] * arv[1] +
                   acc[i][2][reg] * arv[2] + acc[i][3][reg] * arv[3];
#pragma unroll
        for (int mm = 1; mm < 16; mm <<= 1) {
          dl += __shfl_xor(dl, mm);
          dr += __shfl_xor(dr, mm);
        }
        int row_g = bm0 + wm + i * 16 + q * 4 + reg;
        if (r16 == 0 && row_g < M) {
          if (MODE == 0) {
            elp[(size_t)row_g * 4 + head] = dl;
            erp[(size_t)row_g * 4 + head] = dr;
          } else {
            elp[row_g] = dl;
            erp[row_g] = dr;
          }
        }
      }
    }
  }
}

// ---------- CSR build ----------
__launch_bounds__(256)
__global__ void hist_k(const int* __restrict__ dst, int* __restrict__ cnt) {
  int e = blockIdx.x * 256 + threadIdx.x;
  if (e < N_EDGES) atomicAdd(cnt + dst[e], 1);
}

// phase A: per-block inclusive scan of 1024 counts -> off[i+1], block total -> partials
__launch_bounds__(1024)
__global__ void scanA_k(const int* __restrict__ cnt, int* __restrict__ off,
                        int* __restrict__ partials) {
  __shared__ int buf[1024];
  int i = blockIdx.x * 1024 + threadIdx.x;
  int v = (i < N_NODES) ? cnt[i] : 0;
  buf[threadIdx.x] = v;
  __syncthreads();
#pragma unroll
  for (int s = 1; s < 1024; s <<= 1) {
    int t = (threadIdx.x >= s) ? buf[threadIdx.x - s] : 0;
    __syncthreads();
    buf[threadIdx.x] += t;
    __syncthreads();
  }
  if (i < N_NODES) off[i + 1] = buf[threadIdx.x];
  if (threadIdx.x == 1023) partials[blockIdx.x] = buf[1023];
}

// phase B: one wave exclusive-scans the 49 block totals
__launch_bounds__(64)
__global__ void scanB_k(int* __restrict__ partials) {
  int t = threadIdx.x;
  int v = (t < SCAN_BLK) ? partials[t] : 0;
  int orig = v;
#pragma unroll
  for (int s = 1; s < 64; s <<= 1) {
    int u = __shfl_up(v, s);
    if (t >= s) v += u;
  }
  if (t < SCAN_BLK) partials[t] = v - orig;
}

// phase C: add block prefix; emit cursor (= exclusive offset)
__launch_bounds__(1024)
__global__ void scanC_k(const int* __restrict__ cnt, int* __restrict__ off,
                        const int* __restrict__ partials, int* __restrict__ cursor) {
  int i = blockIdx.x * 1024 + threadIdx.x;
  if (i == 0) off[0] = 0;
  if (i < N_NODES) {
    int o = off[i + 1] + partials[blockIdx.x];
    off[i + 1] = o;
    cursor[i] = o - cnt[i];
  }
}

// scatter: store PRE-GATHERED src (kills one indirection in the agg loops)
__launch_bounds__(256)
__global__ void scatter_k(const int* __restrict__ src, const int* __restrict__ dst,
                          int* __restrict__ cursor, int* __restrict__ csr_src) {
  int e = blockIdx.x * 256 + threadIdx.x;
  if (e >= N_EDGES) return;
  int p = atomicAdd(cursor + dst[e], 1);
  csr_src[p] = src[e];
}

// ---------- layer-1 single-pass online softmax + aggregate + bias + ELU ----------
__launch_bounds__(256)
__global__ void agg1_k(const int* __restrict__ csr_src, const int* __restrict__ off,
                       const float* __restrict__ el, const float* __restrict__ er,
                       const short* __restrict__ ft, const float* __restrict__ bias,
                       short* __restrict__ h1) {
  int node = blockIdx.x * 4 + (threadIdx.x >> 6);
  int lane = threadIdx.x & 63;
  if (node >= N_NODES) return;
  int beg = off[node], end = off[node + 1];
  int h = lane >> 4;
  float erh = er[(size_t)node * 4 + h];
  float m = -INFINITY, denom = 0.f;
  float4 acc = make_float4(0.f, 0.f, 0.f, 0.f);
  for (int i = beg; i < end; ++i) {
    int s = csr_src[i];
    float e = leaky(el[(size_t)s * 4 + h] + erh);
    uint2 u = *(const uint2*)(ft + (size_t)s * 256 + lane * 4);
    float mn = fmaxf(m, e);
    float sc = __expf(m - mn);
    float w = __expf(e - mn);
    denom = denom * sc + w;
    acc.x = acc.x * sc + w * bflo(u.x);
    acc.y = acc.y * sc + w * bfhi(u.x);
    acc.z = acc.z * sc + w * bflo(u.y);
    acc.w = acc.w * sc + w * bfhi(u.y);
    m = mn;
  }
  float inv = (end > beg) ? 1.f / denom : 0.f;
  float4 b = *(const float4*)(bias + lane * 4);
  float4 v;
  v.x = acc.x * inv + b.x;
  v.y = acc.y * inv + b.y;
  v.z = acc.z * inv + b.z;
  v.w = acc.w * inv + b.w;
  v.x = v.x > 0.f ? v.x : expm1f(v.x);
  v.y = v.y > 0.f ? v.y : expm1f(v.y);
  v.z = v.z > 0.f ? v.z : expm1f(v.z);
  v.w = v.w > 0.f ? v.w : expm1f(v.w);
  uint2 o;
  o.x = pack2(v.x, v.y);
  o.y = pack2(v.z, v.w);
  *(uint2*)(h1 + (size_t)node * 256 + lane * 4) = o;
}

// ---------- layer-2 single-pass online softmax + aggregate + residual ----------
__launch_bounds__(256)
__global__ void agg2_k(const int* __restrict__ csr_src, const int* __restrict__ off,
                       const float* __restrict__ el, const float* __restrict__ er,
                       const short* __restrict__ ft, float* __restrict__ out) {
  int node = blockIdx.x * 4 + (threadIdx.x >> 6);
  int lane = threadIdx.x & 63;
  if (node >= N_NODES) return;
  int beg = off[node], end = off[node + 1];
  float erd = er[node];
  float m = -INFINITY, denom = 0.f, acc = 0.f;
  for (int i = beg; i < end; ++i) {
    int s = csr_src[i];
    float e = leaky(el[s] + erd);
    float f = bflo((unsigned)(unsigned short)ft[(size_t)s * 64 + lane]);
    float mn = fmaxf(m, e);
    float sc = __expf(m - mn);
    float w = __expf(e - mn);
    denom = denom * sc + w;
    acc = acc * sc + w * f;
    m = mn;
  }
  float r = (end > beg) ? acc / denom : 0.f;
  out[(size_t)node * 64 + lane] += r;
}

// ---------- launch ----------
extern "C" void kernel_launch(void* const* d_in, const int* in_sizes, int n_in,
                              void* d_out, int out_size, void* d_ws, size_t ws_size,
                              hipStream_t stream) {
  const float* feat  = (const float*)d_in[0];
  const int*   src   = (const int*)d_in[1];
  const int*   dst   = (const int*)d_in[2];
  const float* W1    = (const float*)d_in[3];
  const float* al1   = (const float*)d_in[4];
  const float* ar1   = (const float*)d_in[5];
  const float* b1    = (const float*)d_in[6];
  const float* W2    = (const float*)d_in[7];
  const float* al2   = (const float*)d_in[8];
  const float* ar2   = (const float*)d_in[9];
  const float* b2    = (const float*)d_in[10];
  const float* resW2 = (const float*)d_in[11];
  float* out = (float*)d_out;

  char* p = (char*)d_ws;
  short* ft1b = (short*)p; p += (size_t)N_NODES * 256 * 2;
  short* h1b  = (short*)p; p += (size_t)N_NODES * 256 * 2;
  short* ft2b = (short*)p; p += (size_t)N_NODES * 64 * 2;
  short* Wt1  = (short*)p; p += 256 * 256 * 2;
  short* Wt2  = (short*)p; p += 128 * 256 * 2;
  float* el1  = (float*)p; p += (size_t)N_NODES * 4 * 4;
  float* er1  = (float*)p; p += (size_t)N_NODES * 4 * 4;
  float* el2  = (float*)p; p += (size_t)N_NODES * 4;
  float* er2  = (float*)p; p += (size_t)N_NODES * 4;
  int* cnt     = (int*)p;  p += (size_t)N_NODES * 4;
  int* off     = (int*)p;  p += (size_t)(N_NODES + 1) * 4;
  int* cursor  = (int*)p;  p += (size_t)N_NODES * 4;
  int* partials = (int*)p; p += 64 * 4;
  int* csr_src = (int*)p;

  hipMemsetAsync(cnt, 0, (size_t)N_NODES * sizeof(int), stream);

  dim3 blk(256);

  // CSR by dst (shared by both layers)
  hist_k<<<3125, blk, 0, stream>>>(dst, cnt);
  scanA_k<<<SCAN_BLK, 1024, 0, stream>>>(cnt, off, partials);
  scanB_k<<<1, 64, 0, stream>>>(partials);
  scanC_k<<<SCAN_BLK, 1024, 0, stream>>>(cnt, off, partials, cursor);
  scatter_k<<<3125, blk, 0, stream>>>(src, dst, cursor, csr_src);

  // weight packs
  packW_k<<<384, blk, 0, stream>>>(W1, W2, resW2, Wt1, Wt2);

  // layer 1: ft1 = feat @ W1 (bf16 out) + fused el1/er1
  mfma_gemm_k<false, 0><<<dim3(391, 2), blk, 0, stream>>>(
      feat, Wt1, nullptr, al1, ar1, el1, er1, ft1b, nullptr, N_NODES, 256, 256);
  agg1_k<<<12500, blk, 0, stream>>>(csr_src, off, el1, er1, ft1b, b1, h1b);

  // layer 2: [ft2 | res+b2] = h1 @ [W2 | resW2] + fused el2/er2
  mfma_gemm_k<true, 1><<<dim3(391, 1), blk, 0, stream>>>(
      h1b, Wt2, b2, al2, ar2, el2, er2, ft2b, out, N_NODES, 256, 128);
  agg2_k<<<12500, blk, 0, stream>>>(csr_src, off, el2, er2, ft2b, out);
}

// Round 5
// 344.390 us; speedup vs baseline: 10.2871x; 1.2308x over previous
//
#include <hip/hip_runtime.h>
#include <math.h>

#define N_NODES 50000
#define N_EDGES 800000
#define SCAN_BLK 49  // ceil(50000/1024)

typedef __attribute__((ext_vector_type(8))) short bf16x8;
typedef __attribute__((ext_vector_type(4))) float f32x4;

__device__ __forceinline__ float leaky(float x) { return x >= 0.f ? x : 0.2f * x; }
__device__ __forceinline__ unsigned short f2bf(float f) {
  unsigned u = __float_as_uint(f);
  return (unsigned short)((u + 0x7fffu + ((u >> 16) & 1u)) >> 16);
}
__device__ __forceinline__ float bflo(unsigned u) { return __uint_as_float(u << 16); }
__device__ __forceinline__ float bfhi(unsigned u) { return __uint_as_float(u & 0xffff0000u); }
__device__ __forceinline__ unsigned pack2(float a, float b) {
  return (unsigned)f2bf(a) | ((unsigned)f2bf(b) << 16);
}

// ---------- merged weight pack: W1 (256x256) then [W2|resW2] (256x128) ----------
__launch_bounds__(256)
__global__ void packW_k(const float* __restrict__ W1, const float* __restrict__ W2,
                        const float* __restrict__ resW2, short* __restrict__ Wt1,
                        short* __restrict__ Wt2) {
  int b = blockIdx.x;
  if (b < 256) {
    int idx = b * 256 + threadIdx.x;
    int n = idx >> 8, k = idx & 255;
    Wt1[idx] = (short)f2bf(W1[(size_t)k * 256 + n]);
  } else {
    int idx = (b - 256) * 256 + threadIdx.x;
    int n = idx >> 8, k = idx & 255;
    float v = (n < 64) ? W2[(size_t)k * 64 + n] : resW2[(size_t)k * 64 + (n - 64)];
    Wt2[idx] = (short)f2bf(v);
  }
}

// ---------- bf16 MFMA GEMM with fused el/er row-dot epilogue ----------
// 128x128 tile, BK=32, 256 thr = 4 waves (2x2 of 64x64), 4x4 frags of 16x16x32.
// MODE 0: C -> bf16 Cb (ldc=N); every wave covers one head's 64 cols -> el/er (N,4).
// MODE 1: N=128; cols<64 -> bf16 Cb (ld 64) + el/er (N,) from wn==0 waves;
//         cols>=64 -> fp32 Cf = acc + bias[col-64].
template <bool A_BF16, int MODE>
__launch_bounds__(256)
__global__ void mfma_gemm_k(const void* __restrict__ Ap, const short* __restrict__ Bt,
                            const float* __restrict__ bias, const float* __restrict__ al,
                            const float* __restrict__ ar, float* __restrict__ elp,
                            float* __restrict__ erp, short* __restrict__ Cb,
                            float* __restrict__ Cf, int M, int K, int N) {
  __shared__ short As[4][128][8];  // [k-quad][row][k-in-quad]
  __shared__ short Bs[4][128][8];  // [k-quad][col][k-in-quad]
  const int tid = threadIdx.x;
  const int bm0 = blockIdx.x * 128, bn0 = blockIdx.y * 128;
  const int wave = tid >> 6, lane = tid & 63;
  const int wm = (wave & 1) * 64, wn = (wave >> 1) * 64;
  const int q = lane >> 4, r16 = lane & 15;
  const int srow = tid >> 1, sk = (tid & 1) * 16, sq = (tid & 1) * 2;
  f32x4 acc[4][4] = {};

  for (int k0 = 0; k0 < K; k0 += 32) {
    if (A_BF16) {
      const short* A = (const short*)Ap;
      uint4 v0 = {0, 0, 0, 0}, v1 = {0, 0, 0, 0};
      if (bm0 + srow < M) {
        const uint4* p = (const uint4*)(A + (size_t)(bm0 + srow) * K + k0 + sk);
        v0 = p[0];
        v1 = p[1];
      }
      *(uint4*)&As[sq][srow][0] = v0;
      *(uint4*)&As[sq + 1][srow][0] = v1;
    } else {
      const float* A = (const float*)Ap;
      float4 f0 = {0, 0, 0, 0}, f1 = f0, f2 = f0, f3 = f0;
      if (bm0 + srow < M) {
        const float4* p = (const float4*)(A + (size_t)(bm0 + srow) * K + k0 + sk);
        f0 = p[0];
        f1 = p[1];
        f2 = p[2];
        f3 = p[3];
      }
      uint4 v0, v1;
      v0.x = pack2(f0.x, f0.y); v0.y = pack2(f0.z, f0.w);
      v0.z = pack2(f1.x, f1.y); v0.w = pack2(f1.z, f1.w);
      v1.x = pack2(f2.x, f2.y); v1.y = pack2(f2.z, f2.w);
      v1.z = pack2(f3.x, f3.y); v1.w = pack2(f3.z, f3.w);
      *(uint4*)&As[sq][srow][0] = v0;
      *(uint4*)&As[sq + 1][srow][0] = v1;
    }
    {
      const uint4* p = (const uint4*)(Bt + (size_t)(bn0 + srow) * K + k0 + sk);
      *(uint4*)&Bs[sq][srow][0] = p[0];
      *(uint4*)&Bs[sq + 1][srow][0] = p[1];
    }
    __syncthreads();
    bf16x8 af[4], bfr[4];
#pragma unroll
    for (int i = 0; i < 4; ++i) af[i] = *(const bf16x8*)&As[q][wm + i * 16 + r16][0];
#pragma unroll
    for (int j = 0; j < 4; ++j) bfr[j] = *(const bf16x8*)&Bs[q][wn + j * 16 + r16][0];
#pragma unroll
    for (int i = 0; i < 4; ++i)
#pragma unroll
      for (int j = 0; j < 4; ++j)
        acc[i][j] = __builtin_amdgcn_mfma_f32_16x16x32_bf16(af[i], bfr[j], acc[i][j], 0, 0, 0);
    __syncthreads();
  }

  // C store
#pragma unroll
  for (int i = 0; i < 4; ++i) {
#pragma unroll
    for (int reg = 0; reg < 4; ++reg) {
      int row_g = bm0 + wm + i * 16 + q * 4 + reg;
      if (row_g >= M) continue;
#pragma unroll
      for (int j = 0; j < 4; ++j) {
        int col_g = bn0 + wn + j * 16 + r16;
        float v = acc[i][j][reg];
        if (MODE == 0) {
          Cb[(size_t)row_g * N + col_g] = (short)f2bf(v);
        } else {
          if (col_g < 64)
            Cb[(size_t)row_g * 64 + col_g] = (short)f2bf(v);
          else
            Cf[(size_t)row_g * 64 + (col_g - 64)] = v + bias[col_g - 64];
        }
      }
    }
  }

  // fused el/er row-dot: this wave's 64 cols are exactly one head
  if (MODE == 0 || wn == 0) {
    const int head = (bn0 + wn) >> 6;
    float alv[4], arv[4];
#pragma unroll
    for (int j = 0; j < 4; ++j) {
      alv[j] = al[((MODE == 0) ? head * 64 : 0) + j * 16 + r16];
      arv[j] = ar[((MODE == 0) ? head * 64 : 0) + j * 16 + r16];
    }
#pragma unroll
    for (int i = 0; i < 4; ++i) {
#pragma unroll
      for (int reg = 0; reg < 4; ++reg) {
        float dl = acc[i][0][reg] * alv[0] + acc[i][1][reg] * alv[1] +
                   acc[i][2][reg] * alv[2] + acc[i][3][reg] * alv[3];
        float dr = acc[i][0][reg] * arv[0] + acc[i][1][reg] * arv[1] +
                   acc[i][2][reg] * arv[2] + acc[i][3][reg] * arv[3];
#pragma unroll
        for (int mm = 1; mm < 16; mm <<= 1) {
          dl += __shfl_xor(dl, mm);
          dr += __shfl_xor(dr, mm);
        }
        int row_g = bm0 + wm + i * 16 + q * 4 + reg;
        if (r16 == 0 && row_g < M) {
          if (MODE == 0) {
            elp[(size_t)row_g * 4 + head] = dl;
            erp[(size_t)row_g * 4 + head] = dr;
          } else {
            elp[row_g] = dl;
            erp[row_g] = dr;
          }
        }
      }
    }
  }
}

// ---------- CSR build ----------
__launch_bounds__(256)
__global__ void hist_k(const int* __restrict__ dst, int* __restrict__ cnt) {
  int e = blockIdx.x * 256 + threadIdx.x;
  if (e < N_EDGES) atomicAdd(cnt + dst[e], 1);
}

__launch_bounds__(1024)
__global__ void scanA_k(const int* __restrict__ cnt, int* __restrict__ off,
                        int* __restrict__ partials) {
  __shared__ int buf[1024];
  int i = blockIdx.x * 1024 + threadIdx.x;
  int v = (i < N_NODES) ? cnt[i] : 0;
  buf[threadIdx.x] = v;
  __syncthreads();
#pragma unroll
  for (int s = 1; s < 1024; s <<= 1) {
    int t = (threadIdx.x >= s) ? buf[threadIdx.x - s] : 0;
    __syncthreads();
    buf[threadIdx.x] += t;
    __syncthreads();
  }
  if (i < N_NODES) off[i + 1] = buf[threadIdx.x];
  if (threadIdx.x == 1023) partials[blockIdx.x] = buf[1023];
}

__launch_bounds__(64)
__global__ void scanB_k(int* __restrict__ partials) {
  int t = threadIdx.x;
  int v = (t < SCAN_BLK) ? partials[t] : 0;
  int orig = v;
#pragma unroll
  for (int s = 1; s < 64; s <<= 1) {
    int u = __shfl_up(v, s);
    if (t >= s) v += u;
  }
  if (t < SCAN_BLK) partials[t] = v - orig;
}

__launch_bounds__(1024)
__global__ void scanC_k(const int* __restrict__ cnt, int* __restrict__ off,
                        const int* __restrict__ partials, int* __restrict__ cursor) {
  int i = blockIdx.x * 1024 + threadIdx.x;
  if (i == 0) off[0] = 0;
  if (i < N_NODES) {
    int o = off[i + 1] + partials[blockIdx.x];
    off[i + 1] = o;
    cursor[i] = o - cnt[i];
  }
}

__launch_bounds__(256)
__global__ void scatter_k(const int* __restrict__ src, const int* __restrict__ dst,
                          int* __restrict__ cursor, int* __restrict__ csr_src) {
  int e = blockIdx.x * 256 + threadIdx.x;
  if (e >= N_EDGES) return;
  int p = atomicAdd(cursor + dst[e], 1);
  csr_src[p] = src[e];
}

// ---------- layer-1 single-pass online softmax, 4-edge unrolled ----------
__launch_bounds__(256)
__global__ void agg1_k(const int* __restrict__ csr_src, const int* __restrict__ off,
                       const float* __restrict__ el, const float* __restrict__ er,
                       const short* __restrict__ ft, const float* __restrict__ bias,
                       short* __restrict__ h1) {
  int node = blockIdx.x * 4 + (threadIdx.x >> 6);
  int lane = threadIdx.x & 63;
  if (node >= N_NODES) return;
  int beg = off[node], end = off[node + 1];
  int h = lane >> 4;
  float erh = er[(size_t)node * 4 + h];
  float m = -INFINITY, denom = 0.f;
  float4 acc = make_float4(0.f, 0.f, 0.f, 0.f);
  int i = beg;
  for (; i + 4 <= end; i += 4) {
    int s0 = csr_src[i + 0], s1 = csr_src[i + 1];
    int s2 = csr_src[i + 2], s3 = csr_src[i + 3];
    float e0 = leaky(el[(size_t)s0 * 4 + h] + erh);
    float e1 = leaky(el[(size_t)s1 * 4 + h] + erh);
    float e2 = leaky(el[(size_t)s2 * 4 + h] + erh);
    float e3 = leaky(el[(size_t)s3 * 4 + h] + erh);
    uint2 u0 = *(const uint2*)(ft + (size_t)s0 * 256 + lane * 4);
    uint2 u1 = *(const uint2*)(ft + (size_t)s1 * 256 + lane * 4);
    uint2 u2 = *(const uint2*)(ft + (size_t)s2 * 256 + lane * 4);
    uint2 u3 = *(const uint2*)(ft + (size_t)s3 * 256 + lane * 4);
    float mn = fmaxf(m, fmaxf(fmaxf(e0, e1), fmaxf(e2, e3)));
    float sc = __expf(m - mn);
    float w0 = __expf(e0 - mn), w1 = __expf(e1 - mn);
    float w2 = __expf(e2 - mn), w3 = __expf(e3 - mn);
    denom = denom * sc + ((w0 + w1) + (w2 + w3));
    acc.x = acc.x * sc + ((w0 * bflo(u0.x) + w1 * bflo(u1.x)) + (w2 * bflo(u2.x) + w3 * bflo(u3.x)));
    acc.y = acc.y * sc + ((w0 * bfhi(u0.x) + w1 * bfhi(u1.x)) + (w2 * bfhi(u2.x) + w3 * bfhi(u3.x)));
    acc.z = acc.z * sc + ((w0 * bflo(u0.y) + w1 * bflo(u1.y)) + (w2 * bflo(u2.y) + w3 * bflo(u3.y)));
    acc.w = acc.w * sc + ((w0 * bfhi(u0.y) + w1 * bfhi(u1.y)) + (w2 * bfhi(u2.y) + w3 * bfhi(u3.y)));
    m = mn;
  }
  for (; i < end; ++i) {
    int s = csr_src[i];
    float e = leaky(el[(size_t)s * 4 + h] + erh);
    uint2 u = *(const uint2*)(ft + (size_t)s * 256 + lane * 4);
    float mn = fmaxf(m, e);
    float sc = __expf(m - mn);
    float w = __expf(e - mn);
    denom = denom * sc + w;
    acc.x = acc.x * sc + w * bflo(u.x);
    acc.y = acc.y * sc + w * bfhi(u.x);
    acc.z = acc.z * sc + w * bflo(u.y);
    acc.w = acc.w * sc + w * bfhi(u.y);
    m = mn;
  }
  float inv = (end > beg) ? 1.f / denom : 0.f;
  float4 b = *(const float4*)(bias + lane * 4);
  float4 v;
  v.x = acc.x * inv + b.x;
  v.y = acc.y * inv + b.y;
  v.z = acc.z * inv + b.z;
  v.w = acc.w * inv + b.w;
  v.x = v.x > 0.f ? v.x : expm1f(v.x);
  v.y = v.y > 0.f ? v.y : expm1f(v.y);
  v.z = v.z > 0.f ? v.z : expm1f(v.z);
  v.w = v.w > 0.f ? v.w : expm1f(v.w);
  uint2 o;
  o.x = pack2(v.x, v.y);
  o.y = pack2(v.z, v.w);
  *(uint2*)(h1 + (size_t)node * 256 + lane * 4) = o;
}

// ---------- layer-2 single-pass online softmax + residual, 4-edge unrolled ----------
__launch_bounds__(256)
__global__ void agg2_k(const int* __restrict__ csr_src, const int* __restrict__ off,
                       const float* __restrict__ el, const float* __restrict__ er,
                       const short* __restrict__ ft, float* __restrict__ out) {
  int node = blockIdx.x * 4 + (threadIdx.x >> 6);
  int lane = threadIdx.x & 63;
  if (node >= N_NODES) return;
  int beg = off[node], end = off[node + 1];
  float erd = er[node];
  float m = -INFINITY, denom = 0.f, acc = 0.f;
  int i = beg;
  for (; i + 4 <= end; i += 4) {
    int s0 = csr_src[i + 0], s1 = csr_src[i + 1];
    int s2 = csr_src[i + 2], s3 = csr_src[i + 3];
    float e0 = leaky(el[s0] + erd);
    float e1 = leaky(el[s1] + erd);
    float e2 = leaky(el[s2] + erd);
    float e3 = leaky(el[s3] + erd);
    float f0 = bflo((unsigned)(unsigned short)ft[(size_t)s0 * 64 + lane]);
    float f1 = bflo((unsigned)(unsigned short)ft[(size_t)s1 * 64 + lane]);
    float f2 = bflo((unsigned)(unsigned short)ft[(size_t)s2 * 64 + lane]);
    float f3 = bflo((unsigned)(unsigned short)ft[(size_t)s3 * 64 + lane]);
    float mn = fmaxf(m, fmaxf(fmaxf(e0, e1), fmaxf(e2, e3)));
    float sc = __expf(m - mn);
    float w0 = __expf(e0 - mn), w1 = __expf(e1 - mn);
    float w2 = __expf(e2 - mn), w3 = __expf(e3 - mn);
    denom = denom * sc + ((w0 + w1) + (w2 + w3));
    acc = acc * sc + ((w0 * f0 + w1 * f1) + (w2 * f2 + w3 * f3));
    m = mn;
  }
  for (; i < end; ++i) {
    int s = csr_src[i];
    float e = leaky(el[s] + erd);
    float f = bflo((unsigned)(unsigned short)ft[(size_t)s * 64 + lane]);
    float mn = fmaxf(m, e);
    float sc = __expf(m - mn);
    float w = __expf(e - mn);
    denom = denom * sc + w;
    acc = acc * sc + w * f;
    m = mn;
  }
  float r = (end > beg) ? acc / denom : 0.f;
  out[(size_t)node * 64 + lane] += r;
}

// ---------- launch ----------
extern "C" void kernel_launch(void* const* d_in, const int* in_sizes, int n_in,
                              void* d_out, int out_size, void* d_ws, size_t ws_size,
                              hipStream_t stream) {
  const float* feat  = (const float*)d_in[0];
  const int*   src   = (const int*)d_in[1];
  const int*   dst   = (const int*)d_in[2];
  const float* W1    = (const float*)d_in[3];
  const float* al1   = (const float*)d_in[4];
  const float* ar1   = (const float*)d_in[5];
  const float* b1    = (const float*)d_in[6];
  const float* W2    = (const float*)d_in[7];
  const float* al2   = (const float*)d_in[8];
  const float* ar2   = (const float*)d_in[9];
  const float* b2    = (const float*)d_in[10];
  const float* resW2 = (const float*)d_in[11];
  float* out = (float*)d_out;

  char* p = (char*)d_ws;
  short* ft1b = (short*)p; p += (size_t)N_NODES * 256 * 2;
  short* h1b  = (short*)p; p += (size_t)N_NODES * 256 * 2;
  short* ft2b = (short*)p; p += (size_t)N_NODES * 64 * 2;
  short* Wt1  = (short*)p; p += 256 * 256 * 2;
  short* Wt2  = (short*)p; p += 128 * 256 * 2;
  float* el1  = (float*)p; p += (size_t)N_NODES * 4 * 4;
  float* er1  = (float*)p; p += (size_t)N_NODES * 4 * 4;
  float* el2  = (float*)p; p += (size_t)N_NODES * 4;
  float* er2  = (float*)p; p += (size_t)N_NODES * 4;
  int* cnt     = (int*)p;  p += (size_t)N_NODES * 4;
  int* off     = (int*)p;  p += (size_t)(N_NODES + 1) * 4;
  int* cursor  = (int*)p;  p += (size_t)N_NODES * 4;
  int* partials = (int*)p; p += 64 * 4;
  int* csr_src = (int*)p;

  hipMemsetAsync(cnt, 0, (size_t)N_NODES * sizeof(int), stream);

  dim3 blk(256);

  // CSR by dst (shared by both layers)
  hist_k<<<3125, blk, 0, stream>>>(dst, cnt);
  scanA_k<<<SCAN_BLK, 1024, 0, stream>>>(cnt, off, partials);
  scanB_k<<<1, 64, 0, stream>>>(partials);
  scanC_k<<<SCAN_BLK, 1024, 0, stream>>>(cnt, off, partials, cursor);
  scatter_k<<<3125, blk, 0, stream>>>(src, dst, cursor, csr_src);

  // weight packs
  packW_k<<<384, blk, 0, stream>>>(W1, W2, resW2, Wt1, Wt2);

  // layer 1: ft1 = feat @ W1 (bf16 out) + fused el1/er1
  mfma_gemm_k<false, 0><<<dim3(391, 2), blk, 0, stream>>>(
      feat, Wt1, nullptr, al1, ar1, el1, er1, ft1b, nullptr, N_NODES, 256, 256);
  agg1_k<<<12500, blk, 0, stream>>>(csr_src, off, el1, er1, ft1b, b1, h1b);

  // layer 2: [ft2 | res+b2] = h1 @ [W2 | resW2] + fused el2/er2
  mfma_gemm_k<true, 1><<<dim3(391, 1), blk, 0, stream>>>(
      h1b, Wt2, b2, al2, ar2, el2, er2, ft2b, out, N_NODES, 256, 128);
  agg2_k<<<12500, blk, 0, stream>>>(csr_src, off, el2, er2, ft2b, out);
}